// Round 1
// 2342.354 us; speedup vs baseline: 1.0737x; 1.0737x over previous
//
#include <hip/hip_runtime.h>
#include <hip/hip_bf16.h>

// JumpReLU SAE forward:
//   pre  = (x - b_dec) @ W_enc + b_enc          [8192, 16384]
//   feat = pre * (pre > threshold)
//   rec  = feat @ W_dec + b_dec                 [8192, 2048]
// out = [rec (8192*2048) | feat (8192*16384)] fp32
//
// GEMM: 256x256 tile, BK=64, 512 threads (2x4 waves), 8-phase-style schedule:
//   T1 XCD swizzle, T2 st-swizzled LDS (pre-swizzled global_load_lds source),
//   T3/T4 per-phase stage interleave + counted vmcnt(2), T5 setprio around MFMA.

typedef __bf16 bf16x8 __attribute__((ext_vector_type(8)));
typedef float  f32x4  __attribute__((ext_vector_type(4)));

__device__ __forceinline__ short f2bf(float f) {
    unsigned u = __float_as_uint(f);
    unsigned r = u + 0x7FFF + ((u >> 16) & 1);   // round-to-nearest-even
    return (short)(r >> 16);
}

__device__ __forceinline__ void gl_lds16(const void* g, void* l) {
    __builtin_amdgcn_global_load_lds(
        (const __attribute__((address_space(1))) unsigned int*)g,
        (__attribute__((address_space(3))) unsigned int*)l, 16, 0, 0);
}

__device__ __forceinline__ void fence_bar() {
    asm volatile("" ::: "memory");
    __builtin_amdgcn_s_barrier();
    asm volatile("" ::: "memory");
}

// ---- prep: xb[m][k] = bf16(x[m][k] - b_dec[k]), d_model = 2048 ----
__global__ __launch_bounds__(256) void prep_x(const float* __restrict__ x,
                                              const float* __restrict__ b_dec,
                                              short* __restrict__ xb) {
    int idx = (blockIdx.x * 256 + threadIdx.x) * 4;
    float4 v = *(const float4*)(x + idx);
    int k = idx & 2047;
    float4 b = *(const float4*)(b_dec + k);
    short4 o;
    o.x = f2bf(v.x - b.x);
    o.y = f2bf(v.y - b.y);
    o.z = f2bf(v.z - b.z);
    o.w = f2bf(v.w - b.w);
    *(short4*)(xb + idx) = o;
}

// ---- transpose + fp32->bf16: in [R][C] fp32 -> out [C][R] bf16 ----
// 64(R) x 32(C) tile; 4B/lane coalesced writes; conflict-free [32][66] LDS.
__global__ __launch_bounds__(256) void transpose_cvt64(const float* __restrict__ in,
                                                       short* __restrict__ out,
                                                       int R, int C) {
    __shared__ short t[32][66];
    const int tid = threadIdx.x;
    const int c0 = blockIdx.x * 32;
    const int r0 = blockIdx.y * 64;
#pragma unroll
    for (int i = 0; i < 8; ++i) {
        int idx = tid + i * 256;
        int r = idx >> 5, c = idx & 31;
        t[c][r] = f2bf(in[(size_t)(r0 + r) * C + (c0 + c)]);
    }
    __syncthreads();
#pragma unroll
    for (int i = 0; i < 4; ++i) {
        int idx = tid + i * 256;
        int orow = idx >> 5, chunk = idx & 31;
        *(short2*)(&out[(size_t)(c0 + orow) * R + r0 + chunk * 2]) =
            *(const short2*)(&t[orow][chunk * 2]);
    }
}

// ---- GEMM: C[M][N] = A[M][K] * Bt[N][K]^T (+bias, optional JumpReLU) ----
// 256x256 tile, BK=64, 512 threads = 8 waves (wm 0..1, wn 0..3),
// per-wave 128x64 output = acc[8][4] 16x16 frags.
// LDS: double-buffered A,B tiles [256][64] bf16, XOR-swizzled:
//   logical (row, cbyte) lives at byte row*128 + (cbyte ^ ((row&7)<<4)).
// global_load_lds writes linearly -> source col pre-swizzled (rule #21).
__global__ __launch_bounds__(512, 1) void gemm256(
    const short* __restrict__ A, const short* __restrict__ Bt,
    const float* __restrict__ bias, const float* __restrict__ thr,
    float* __restrict__ Cf, short* __restrict__ Cb,
    int M, int N, int K) {
    __shared__ short As[2][256 * 64];
    __shared__ short Bs[2][256 * 64];

    const int tid  = threadIdx.x;
    const int lane = tid & 63;
    const int wave = tid >> 6;
    const int wm   = wave >> 2;     // 0..1
    const int wn   = wave & 3;      // 0..3

    // T1: XCD-aware block swizzle (grid total is a multiple of 8 here)
    const int Mt   = M >> 8;
    const int nwg  = gridDim.x * gridDim.y;
    const int orig = blockIdx.y * gridDim.x + blockIdx.x;
    const int wg   = (orig & 7) * (nwg >> 3) + (orig >> 3);
    const int bm   = wg % Mt;
    const int bn   = wg / Mt;

    const short* Abase = A  + (size_t)bm * 256 * K;
    const short* Bbase = Bt + (size_t)bn * 256 * K;

    // staging constants: thread covers LDS bytes tid*16 of a 128x64 half-tile
    // (row = tid>>3, slot = tid&7); source col pre-swizzled so that a
    // swizzled READ returns the logical element (involution).
    const int srow = tid >> 3;                                       // 0..63
    const int csel = ((((tid & 7) << 4) ^ ((srow & 7) << 4)) >> 1);  // elem col

    // frag-read constants
    const int mrow = lane & 15;
    const int hi16 = (lane >> 4) << 4;     // 0/16/32/48 byte k-offset
    const int swz  = (mrow & 7) << 4;

    f32x4 acc[8][4];
#pragma unroll
    for (int i = 0; i < 8; ++i)
#pragma unroll
        for (int j = 0; j < 4; ++j)
            acc[i][j] = (f32x4){0.f, 0.f, 0.f, 0.f};

    // h: 0=A rows 0-127, 1=A rows 128-255, 2=B rows 0-127, 3=B rows 128-255
    auto stage = [&](int buf, int h, int t) {
        const short* gb = ((h < 2) ? Abase : Bbase)
                          + (size_t)((h & 1) * 128 + srow) * K + t * 64 + csel;
        char* lb = (char*)((h < 2) ? As[buf] : Bs[buf]) + (h & 1) * 16384 + wave * 1024;
        gl_lds16(gb, lb);
        gl_lds16(gb + (size_t)64 * K, lb + 8192);
    };

    const int NT = K >> 6;

    // prologue: tile0 fully + A0 of tile1 in flight; retire tile0 only.
    stage(0, 0, 0); stage(0, 1, 0); stage(0, 2, 0); stage(0, 3, 0);
    stage(1, 0, 1);
    asm volatile("s_waitcnt vmcnt(2)" ::: "memory");
    fence_bar();

    bf16x8 af[4][2], bq[2][2];

    for (int t = 0; t < NT; ++t) {
        const int cur = t & 1, nxt = cur ^ 1;
        const char* Ard = (const char*)As[cur] + (wm * 128 + mrow) * 128;
        const char* Brd = (const char*)Bs[cur] + (wn * 64 + mrow) * 128;

        // ---- P0: Mlo x Nlo ---- (A1 of t+1: its region died at t-1's P2)
#pragma unroll
        for (int mi = 0; mi < 4; ++mi)
#pragma unroll
            for (int kk = 0; kk < 2; ++kk)
                af[mi][kk] = *(const bf16x8*)(Ard + mi * 2048 + ((kk * 64 + hi16) ^ swz));
#pragma unroll
        for (int ni = 0; ni < 2; ++ni)
#pragma unroll
            for (int kk = 0; kk < 2; ++kk)
                bq[ni][kk] = *(const bf16x8*)(Brd + ni * 2048 + ((kk * 64 + hi16) ^ swz));
        if (t + 1 < NT) stage(nxt, 1, t + 1);
        fence_bar();
        asm volatile("s_waitcnt lgkmcnt(0)" ::: "memory");
        __builtin_amdgcn_s_setprio(1);
#pragma unroll
        for (int mi = 0; mi < 4; ++mi)
#pragma unroll
            for (int ni = 0; ni < 2; ++ni)
#pragma unroll
                for (int kk = 0; kk < 2; ++kk)
                    acc[mi][ni] = __builtin_amdgcn_mfma_f32_16x16x32_bf16(
                        af[mi][kk], bq[ni][kk], acc[mi][ni], 0, 0, 0);
        __builtin_amdgcn_s_setprio(0);
        fence_bar();

        // ---- P1: Mlo x Nhi ---- (B0 of t+1: died at t-1's P3)
#pragma unroll
        for (int ni = 0; ni < 2; ++ni)
#pragma unroll
            for (int kk = 0; kk < 2; ++kk)
                bq[ni][kk] = *(const bf16x8*)(Brd + (2 + ni) * 2048 + ((kk * 64 + hi16) ^ swz));
        if (t + 1 < NT) stage(nxt, 2, t + 1);
        fence_bar();
        asm volatile("s_waitcnt lgkmcnt(0)" ::: "memory");
        __builtin_amdgcn_s_setprio(1);
#pragma unroll
        for (int mi = 0; mi < 4; ++mi)
#pragma unroll
            for (int ni = 0; ni < 2; ++ni)
#pragma unroll
                for (int kk = 0; kk < 2; ++kk)
                    acc[mi][2 + ni] = __builtin_amdgcn_mfma_f32_16x16x32_bf16(
                        af[mi][kk], bq[ni][kk], acc[mi][2 + ni], 0, 0, 0);
        __builtin_amdgcn_s_setprio(0);
        fence_bar();

        // ---- P2: Mhi x Nhi ---- (B1 of t+1: died at t-1's P3)
#pragma unroll
        for (int mi = 0; mi < 4; ++mi)
#pragma unroll
            for (int kk = 0; kk < 2; ++kk)
                af[mi][kk] = *(const bf16x8*)(Ard + (4 + mi) * 2048 + ((kk * 64 + hi16) ^ swz));
        if (t + 1 < NT) stage(nxt, 3, t + 1);
        fence_bar();
        asm volatile("s_waitcnt lgkmcnt(0)" ::: "memory");
        __builtin_amdgcn_s_setprio(1);
#pragma unroll
        for (int mi = 0; mi < 4; ++mi)
#pragma unroll
            for (int ni = 0; ni < 2; ++ni)
#pragma unroll
                for (int kk = 0; kk < 2; ++kk)
                    acc[4 + mi][2 + ni] = __builtin_amdgcn_mfma_f32_16x16x32_bf16(
                        af[mi][kk], bq[ni][kk], acc[4 + mi][2 + ni], 0, 0, 0);
        __builtin_amdgcn_s_setprio(0);
        fence_bar();

        // ---- P3: Mhi x Nlo ---- (A0 of t+2 into cur: A region died at P2)
#pragma unroll
        for (int ni = 0; ni < 2; ++ni)
#pragma unroll
            for (int kk = 0; kk < 2; ++kk)
                bq[ni][kk] = *(const bf16x8*)(Brd + ni * 2048 + ((kk * 64 + hi16) ^ swz));
        if (t + 2 < NT) stage(cur, 0, t + 2);
        fence_bar();
        asm volatile("s_waitcnt lgkmcnt(0)" ::: "memory");
        __builtin_amdgcn_s_setprio(1);
#pragma unroll
        for (int mi = 0; mi < 4; ++mi)
#pragma unroll
            for (int ni = 0; ni < 2; ++ni)
#pragma unroll
                for (int kk = 0; kk < 2; ++kk)
                    acc[4 + mi][ni] = __builtin_amdgcn_mfma_f32_16x16x32_bf16(
                        af[mi][kk], bq[ni][kk], acc[4 + mi][ni], 0, 0, 0);
        __builtin_amdgcn_s_setprio(0);
        // boundary wait: retire all of tile t+1 (8 loads), keep A0(t+2) in flight
        if (t + 2 < NT) {
            asm volatile("s_waitcnt vmcnt(2)" ::: "memory");
        } else if (t + 1 < NT) {
            asm volatile("s_waitcnt vmcnt(0)" ::: "memory");
        }
        fence_bar();
    }

    // ---- epilogue: D[row=(lane>>4)*4+r][col=lane&15] per 16x16 frag ----
    const int colb = bn * 256 + wn * 64 + mrow;
    const int rowb = bm * 256 + wm * 128 + ((lane >> 4) << 2);
    float bz[4], tz[4];
#pragma unroll
    for (int ni = 0; ni < 4; ++ni) {
        bz[ni] = bias[colb + ni * 16];
        tz[ni] = thr ? thr[colb + ni * 16] : 0.f;
    }
#pragma unroll
    for (int mi = 0; mi < 8; ++mi) {
#pragma unroll
        for (int ni = 0; ni < 4; ++ni) {
#pragma unroll
            for (int r = 0; r < 4; ++r) {
                float v = acc[mi][ni][r] + bz[ni];
                if (thr) v = (v > tz[ni]) ? v : 0.f;
                size_t off = (size_t)(rowb + mi * 16 + r) * N + colb + ni * 16;
                Cf[off] = v;
                if (Cb) Cb[off] = f2bf(v);
            }
        }
    }
}

extern "C" void kernel_launch(void* const* d_in, const int* in_sizes, int n_in,
                              void* d_out, int out_size, void* d_ws, size_t ws_size,
                              hipStream_t stream) {
    const float* x      = (const float*)d_in[0];   // [8192][2048]
    const float* W_enc  = (const float*)d_in[1];   // [2048][16384]
    const float* b_enc  = (const float*)d_in[2];   // [16384]
    const float* thr    = (const float*)d_in[3];   // [16384]
    const float* W_dec  = (const float*)d_in[4];   // [16384][2048]
    const float* b_dec  = (const float*)d_in[5];   // [2048]

    const int N = 8192, DM = 2048, DS = 16384;

    float* recon = (float*)d_out;                       // [8192][2048]
    float* feats = (float*)d_out + (size_t)N * DM;      // [8192][16384]

    char* ws = (char*)d_ws;
    short* xb    = (short*)ws;                            // 32MB  [8192][2048]
    short* wencT = (short*)(ws + ((size_t)32 << 20));     // 64MB  [16384][2048]
    short* wdecT = (short*)(ws + ((size_t)96 << 20));     // 64MB  [2048][16384]
    short* fb    = (short*)(ws + ((size_t)160 << 20));    // 256MB [8192][16384]

    prep_x<<<(N * DM) / (256 * 4), 256, 0, stream>>>(x, b_dec, xb);
    transpose_cvt64<<<dim3(DS / 32, DM / 64), 256, 0, stream>>>(W_enc, wencT, DM, DS);
    transpose_cvt64<<<dim3(DM / 32, DS / 64), 256, 0, stream>>>(W_dec, wdecT, DS, DM);

    // encode + JumpReLU: feats = JumpReLU((x-b_dec) @ W_enc + b_enc)
    gemm256<<<dim3(N / 256, DS / 256), 512, 0, stream>>>(
        xb, wencT, b_enc, thr, feats, fb, N, DS, DM);
    // decode: recon = feats @ W_dec + b_dec
    gemm256<<<dim3(N / 256, DM / 256), 512, 0, stream>>>(
        fb, wdecT, b_dec, nullptr, recon, nullptr, N, DM, DS);
}

// Round 2
// 2221.042 us; speedup vs baseline: 1.1324x; 1.0546x over previous
//
#include <hip/hip_runtime.h>
#include <hip/hip_bf16.h>

// JumpReLU SAE forward:
//   pre  = (x - b_dec) @ W_enc + b_enc          [8192, 16384]
//   feat = pre * (pre > threshold)
//   rec  = feat @ W_dec + b_dec                 [8192, 2048]
// out = [rec (8192*2048) | feat (8192*16384)] fp32
//
// GEMM: 256x256 tile, BK=64, 512 threads (2x4 waves), 4-phase schedule,
// single barrier/phase, 2-tile-deep staging (1 half-tile per phase),
// boundary vmcnt(4) (never drains in steady state), T1 XCD swizzle,
// T2 st-swizzled LDS, T5 setprio. Frags read once per tile (24 ds_read_b128).

typedef __bf16 bf16x8 __attribute__((ext_vector_type(8)));
typedef float  f32x4  __attribute__((ext_vector_type(4)));

__device__ __forceinline__ short f2bf(float f) {
    unsigned u = __float_as_uint(f);
    unsigned r = u + 0x7FFF + ((u >> 16) & 1);   // round-to-nearest-even
    return (short)(r >> 16);
}

__device__ __forceinline__ void gl_lds16(const void* g, void* l) {
    __builtin_amdgcn_global_load_lds(
        (const __attribute__((address_space(1))) unsigned int*)g,
        (__attribute__((address_space(3))) unsigned int*)l, 16, 0, 0);
}

__device__ __forceinline__ void fence_bar() {
    asm volatile("" ::: "memory");
    __builtin_amdgcn_s_barrier();
    asm volatile("" ::: "memory");
}

// ---- prep: xb[m][k] = bf16(x[m][k] - b_dec[k]), d_model = 2048 ----
__global__ __launch_bounds__(256) void prep_x(const float* __restrict__ x,
                                              const float* __restrict__ b_dec,
                                              short* __restrict__ xb) {
    int idx = (blockIdx.x * 256 + threadIdx.x) * 4;
    float4 v = *(const float4*)(x + idx);
    int k = idx & 2047;
    float4 b = *(const float4*)(b_dec + k);
    short4 o;
    o.x = f2bf(v.x - b.x);
    o.y = f2bf(v.y - b.y);
    o.z = f2bf(v.z - b.z);
    o.w = f2bf(v.w - b.w);
    *(short4*)(xb + idx) = o;
}

// ---- transpose + fp32->bf16: in [R][C] fp32 -> out [C][R] bf16 ----
// 128(R) x 32(C) tile; short4 (8B) coalesced writes; [32][130] LDS (pad).
__global__ __launch_bounds__(256) void transpose_cvt128(const float* __restrict__ in,
                                                        short* __restrict__ out,
                                                        int R, int C) {
    __shared__ short t[32][130];
    const int tid = threadIdx.x;
    const int c0 = blockIdx.x * 32;
    const int r0 = blockIdx.y * 128;
#pragma unroll
    for (int i = 0; i < 16; ++i) {
        int idx = tid + i * 256;         // 0..4095
        int r = idx >> 5, c = idx & 31;
        t[c][r] = f2bf(in[(size_t)(r0 + r) * C + (c0 + c)]);
    }
    __syncthreads();
#pragma unroll
    for (int i = 0; i < 4; ++i) {
        int idx = tid + i * 256;         // 0..1023
        int oc = idx >> 5, rc = idx & 31;
        short4 v;
        v.x = t[oc][rc * 4 + 0];
        v.y = t[oc][rc * 4 + 1];
        v.z = t[oc][rc * 4 + 2];
        v.w = t[oc][rc * 4 + 3];
        *(short4*)(&out[(size_t)(c0 + oc) * R + r0 + rc * 4]) = v;
    }
}

// ---- GEMM: C[M][N] = A[M][K] * Bt[N][K]^T (+bias, optional JumpReLU) ----
// 256x256 tile, BK=64, 512 threads = 8 waves (wm 0..1, wn 0..3),
// per-wave 128x64 output = acc[8][4] 16x16 frags.
// LDS: double-buffered A,B tiles [256][64] bf16, XOR-swizzled:
//   logical (row, cbyte) lives at byte row*128 + (cbyte ^ ((row&7)<<4)).
// global_load_lds writes linearly -> source col pre-swizzled (rule #21).
//
// Phase liveness (frags read ONCE per tile, kept in regs):
//   P0 reads A rows {0-63,128-191} + B rows {0-31,64-95,128-159,192-223}
//   P1 reads B rows {32-63,96-127,160-191,224-255}
//   P2 reads A rows {64-127,192-255}
//   P3 reads nothing (pure MFMA)
// => half-tile h0/h1 (A) dead after P2; h2/h3 (B) dead after P1.
// Staging (steady state, during tile t): P0: h0(t+1), P1: h1(t+1),
//   P2: h2(t+2), P3: h3(t+2); boundary vmcnt(4) retires tile t+1's 8 loads.
// Min latency cover = 3 phases (>= ~2000 cy >> 900 cy HBM latency).
__global__ __launch_bounds__(512, 1) void gemm256(
    const short* __restrict__ A, const short* __restrict__ Bt,
    const float* __restrict__ bias, const float* __restrict__ thr,
    float* __restrict__ Cf, short* __restrict__ Cb,
    int M, int N, int K) {
    __shared__ short As[2][256 * 64];
    __shared__ short Bs[2][256 * 64];

    const int tid  = threadIdx.x;
    const int lane = tid & 63;
    const int wave = tid >> 6;
    const int wm   = wave >> 2;     // 0..1
    const int wn   = wave & 3;      // 0..3

    // T1: XCD-aware block swizzle (grid total is a multiple of 8 here)
    const int Mt   = M >> 8;
    const int nwg  = gridDim.x * gridDim.y;
    const int orig = blockIdx.y * gridDim.x + blockIdx.x;
    const int wg   = (orig & 7) * (nwg >> 3) + (orig >> 3);
    const int bm   = wg % Mt;
    const int bn   = wg / Mt;

    const short* Abase = A  + (size_t)bm * 256 * K;
    const short* Bbase = Bt + (size_t)bn * 256 * K;

    // staging: thread covers LDS bytes tid*16 of a 128x64 half-tile
    // (row = tid>>3, slot = tid&7); source col pre-swizzled (involution).
    const int srow = tid >> 3;                                       // 0..63
    const int csel = ((((tid & 7) << 4) ^ ((srow & 7) << 4)) >> 1);  // elem col

    // frag-read constants
    const int mrow = lane & 15;
    const int hi16 = (lane >> 4) << 4;     // 0/16/32/48 byte k-offset
    const int swz  = (mrow & 7) << 4;

    f32x4 acc[8][4];
#pragma unroll
    for (int i = 0; i < 8; ++i)
#pragma unroll
        for (int j = 0; j < 4; ++j)
            acc[i][j] = (f32x4){0.f, 0.f, 0.f, 0.f};

    // h: 0=A rows 0-127, 1=A rows 128-255, 2=B rows 0-127, 3=B rows 128-255
    auto stage = [&](int buf, int h, int t) {
        const short* gb = ((h < 2) ? Abase : Bbase)
                          + (size_t)((h & 1) * 128 + srow) * K + t * 64 + csel;
        char* lb = (char*)((h < 2) ? As[buf] : Bs[buf]) + (h & 1) * 16384 + wave * 1024;
        gl_lds16(gb, lb);
        gl_lds16(gb + (size_t)64 * K, lb + 8192);
    };

    const int NT = K >> 6;

    // prologue: tile0 fully; tile1 h2,h3 (h0,h1 staged in t=0's P0/P1)
    stage(0, 0, 0); stage(0, 1, 0); stage(0, 2, 0); stage(0, 3, 0);
    stage(1, 2, 1); stage(1, 3, 1);
    asm volatile("s_waitcnt vmcnt(4)" ::: "memory");   // retire tile0
    fence_bar();

    bf16x8 af[4][2], bqlo[2][2], bqhi[2][2];

    for (int t = 0; t < NT; ++t) {
        const int cur = t & 1, nxt = cur ^ 1;
        const char* Ard = (const char*)As[cur] + (wm * 128 + mrow) * 128;
        const char* Brd = (const char*)Bs[cur] + (wn * 64 + mrow) * 128;

        // ---- P0: Mlo x Nlo ----
#pragma unroll
        for (int mi = 0; mi < 4; ++mi)
#pragma unroll
            for (int kk = 0; kk < 2; ++kk)
                af[mi][kk] = *(const bf16x8*)(Ard + mi * 2048 + ((kk * 64 + hi16) ^ swz));
#pragma unroll
        for (int ni = 0; ni < 2; ++ni)
#pragma unroll
            for (int kk = 0; kk < 2; ++kk)
                bqlo[ni][kk] = *(const bf16x8*)(Brd + ni * 2048 + ((kk * 64 + hi16) ^ swz));
        if (t + 1 < NT) stage(nxt, 0, t + 1);
        __builtin_amdgcn_s_setprio(1);
#pragma unroll
        for (int mi = 0; mi < 4; ++mi)
#pragma unroll
            for (int ni = 0; ni < 2; ++ni)
#pragma unroll
                for (int kk = 0; kk < 2; ++kk)
                    acc[mi][ni] = __builtin_amdgcn_mfma_f32_16x16x32_bf16(
                        af[mi][kk], bqlo[ni][kk], acc[mi][ni], 0, 0, 0);
        __builtin_amdgcn_s_setprio(0);
        fence_bar();

        // ---- P1: Mlo x Nhi ----
#pragma unroll
        for (int ni = 0; ni < 2; ++ni)
#pragma unroll
            for (int kk = 0; kk < 2; ++kk)
                bqhi[ni][kk] = *(const bf16x8*)(Brd + (2 + ni) * 2048 + ((kk * 64 + hi16) ^ swz));
        if (t + 1 < NT) stage(nxt, 1, t + 1);
        __builtin_amdgcn_s_setprio(1);
#pragma unroll
        for (int mi = 0; mi < 4; ++mi)
#pragma unroll
            for (int ni = 0; ni < 2; ++ni)
#pragma unroll
                for (int kk = 0; kk < 2; ++kk)
                    acc[mi][2 + ni] = __builtin_amdgcn_mfma_f32_16x16x32_bf16(
                        af[mi][kk], bqhi[ni][kk], acc[mi][2 + ni], 0, 0, 0);
        __builtin_amdgcn_s_setprio(0);
        fence_bar();

        // ---- P2: Mhi x Nhi ---- (overwrite af with A-hi frags)
#pragma unroll
        for (int mi = 0; mi < 4; ++mi)
#pragma unroll
            for (int kk = 0; kk < 2; ++kk)
                af[mi][kk] = *(const bf16x8*)(Ard + (4 + mi) * 2048 + ((kk * 64 + hi16) ^ swz));
        if (t + 2 < NT) stage(cur, 2, t + 2);
        __builtin_amdgcn_s_setprio(1);
#pragma unroll
        for (int mi = 0; mi < 4; ++mi)
#pragma unroll
            for (int ni = 0; ni < 2; ++ni)
#pragma unroll
                for (int kk = 0; kk < 2; ++kk)
                    acc[4 + mi][2 + ni] = __builtin_amdgcn_mfma_f32_16x16x32_bf16(
                        af[mi][kk], bqhi[ni][kk], acc[4 + mi][2 + ni], 0, 0, 0);
        __builtin_amdgcn_s_setprio(0);
        fence_bar();

        // ---- P3: Mhi x Nlo ---- (pure MFMA: af=A-hi, bqlo from P0)
        if (t + 2 < NT) stage(cur, 3, t + 2);
        __builtin_amdgcn_s_setprio(1);
#pragma unroll
        for (int mi = 0; mi < 4; ++mi)
#pragma unroll
            for (int ni = 0; ni < 2; ++ni)
#pragma unroll
                for (int kk = 0; kk < 2; ++kk)
                    acc[4 + mi][ni] = __builtin_amdgcn_mfma_f32_16x16x32_bf16(
                        af[mi][kk], bqlo[ni][kk], acc[4 + mi][ni], 0, 0, 0);
        __builtin_amdgcn_s_setprio(0);
        // boundary: retire tile t+1's 8 loads, keep t+2's 4 in flight
        if (t + 2 < NT) {
            asm volatile("s_waitcnt vmcnt(4)" ::: "memory");
        } else if (t + 1 < NT) {
            asm volatile("s_waitcnt vmcnt(0)" ::: "memory");
        }
        fence_bar();
    }

    // ---- epilogue: D[row=(lane>>4)*4+r][col=lane&15] per 16x16 frag ----
    const int colb = bn * 256 + wn * 64 + mrow;
    const int rowb = bm * 256 + wm * 128 + ((lane >> 4) << 2);
    float bz[4], tz[4];
#pragma unroll
    for (int ni = 0; ni < 4; ++ni) {
        bz[ni] = bias[colb + ni * 16];
        tz[ni] = thr ? thr[colb + ni * 16] : 0.f;
    }
#pragma unroll
    for (int mi = 0; mi < 8; ++mi) {
#pragma unroll
        for (int ni = 0; ni < 4; ++ni) {
#pragma unroll
            for (int r = 0; r < 4; ++r) {
                float v = acc[mi][ni][r] + bz[ni];
                if (thr) v = (v > tz[ni]) ? v : 0.f;
                size_t off = (size_t)(rowb + mi * 16 + r) * N + colb + ni * 16;
                Cf[off] = v;
                if (Cb) Cb[off] = f2bf(v);
            }
        }
    }
}

extern "C" void kernel_launch(void* const* d_in, const int* in_sizes, int n_in,
                              void* d_out, int out_size, void* d_ws, size_t ws_size,
                              hipStream_t stream) {
    const float* x      = (const float*)d_in[0];   // [8192][2048]
    const float* W_enc  = (const float*)d_in[1];   // [2048][16384]
    const float* b_enc  = (const float*)d_in[2];   // [16384]
    const float* thr    = (const float*)d_in[3];   // [16384]
    const float* W_dec  = (const float*)d_in[4];   // [16384][2048]
    const float* b_dec  = (const float*)d_in[5];   // [2048]

    const int N = 8192, DM = 2048, DS = 16384;

    float* recon = (float*)d_out;                       // [8192][2048]
    float* feats = (float*)d_out + (size_t)N * DM;      // [8192][16384]

    char* ws = (char*)d_ws;
    short* xb    = (short*)ws;                            // 32MB  [8192][2048]
    short* wencT = (short*)(ws + ((size_t)32 << 20));     // 64MB  [16384][2048]
    short* wdecT = (short*)(ws + ((size_t)96 << 20));     // 64MB  [2048][16384]
    short* fb    = (short*)(ws + ((size_t)160 << 20));    // 256MB [8192][16384]

    prep_x<<<(N * DM) / (256 * 4), 256, 0, stream>>>(x, b_dec, xb);
    transpose_cvt128<<<dim3(DS / 32, DM / 128), 256, 0, stream>>>(W_enc, wencT, DM, DS);
    transpose_cvt128<<<dim3(DM / 32, DS / 128), 256, 0, stream>>>(W_dec, wdecT, DS, DM);

    // encode + JumpReLU: feats = JumpReLU((x-b_dec) @ W_enc + b_enc)
    gemm256<<<dim3(N / 256, DS / 256), 512, 0, stream>>>(
        xb, wencT, b_enc, thr, feats, fb, N, DS, DM);
    // decode: recon = feats @ W_dec + b_dec
    gemm256<<<dim3(N / 256, DM / 256), 512, 0, stream>>>(
        fb, wdecT, b_dec, nullptr, recon, nullptr, N, DM, DS);
}